// Round 15
// baseline (42.158 us; speedup 1.0000x reference)
//
#include <hip/hip_runtime.h>

// DecoderLayer: out[k,n,m] = tanh(sum_p w[k,p]*prev[idx[k,p],n,m] + b[k]),
// gated by (#active parents >= 12).  M=2048, K=4096, NN=4096 (64x64), P=16.
//
// R15 = R14 + depth-1 software pipeline on the per-node table loads.
// R12/R14 showed: LDS pipe 41-66% duty, VALU ~37%, time insensitive to
// gather-instr count -> dependency-stall bound. VGPR=44 proves no prefetch:
// each node iter serializes {10 L2 table loads (~300cy)} -> {ds addr calc}
// -> {gathers}. Fix: rotating next-iter table prefetch in named registers,
// pinned above the FMA clusters by the existing sched_barrier(0)s.
// __launch_bounds__(1024,4) caps VGPR at 128 (4 waves/SIMD, 1 block/CU).

#define M_ROWS   2048
#define K_NODES  4096
#define NN       4096
#define POS_TILE 16
#define NTHREADS 1024
#define ROW_B    48                          // bytes per padded bf16 row
#define LDS_BYTES (M_ROWS * ROW_B)           // 98304 = 96 KiB
#define OUT_ELEMS (K_NODES * NN)
#define ACTIVE_THRESHOLD 12

typedef float f32x4 __attribute__((ext_vector_type(4)));
typedef unsigned short u16x8 __attribute__((ext_vector_type(8)));

__device__ __forceinline__ float fast_tanh(float x) {
  float ax = __builtin_fabsf(x);
  float e  = __expf(-2.0f * ax);
  float r  = (1.0f - e) * __builtin_amdgcn_rcpf(1.0f + e);
  return __builtin_copysignf(r, x);
}

__device__ __forceinline__ unsigned short f2bf_rne(float f) {
  unsigned u = __float_as_uint(f);
  u += 0x7FFFu + ((u >> 16) & 1u);           // round-to-nearest-even
  return (unsigned short)(u >> 16);
}

// Gate precompute (off hot path). Runtime-detects isact marshaling:
// any 32-bit word >1 in the first 2048 bytes implies packed bytes.
__global__ __launch_bounds__(256) void act_kernel(
    const int* __restrict__ pidx, const unsigned int* __restrict__ isact,
    float* __restrict__ outact) {
  __shared__ int mode_sh;
  if (threadIdx.x == 0) mode_sh = 0;
  __syncthreads();
  int bad = 0;
  for (int i = threadIdx.x; i < 512; i += 256) bad |= (isact[i] > 1u);
  if (bad) atomicOr(&mode_sh, 1);
  __syncthreads();
  const int shift = mode_sh ? 0 : 2;   // LSB byte of a 0/1 int32 == its value
  const unsigned char* actb = (const unsigned char*)isact;

  int k = blockIdx.x * 256 + threadIdx.x;
  const int4* ip = (const int4*)(pidx + k * 16);
  int4 ia = ip[0], ib = ip[1], ic = ip[2], id4 = ip[3];
  int ids[16] = {ia.x, ia.y, ia.z, ia.w, ib.x, ib.y, ib.z, ib.w,
                 ic.x, ic.y, ic.z, ic.w, id4.x, id4.y, id4.z, id4.w};
  int n = 0;
  #pragma unroll
  for (int p = 0; p < 16; ++p) n += (actb[ids[p] << shift] != 0);
  outact[k] = (n >= ACTIVE_THRESHOLD) ? 1.0f : 0.0f;
}

// unpack-and-FMA one parent: 8 bf16 positions, scalar f32 accs
#define PFMA(vv, wv)                                              \
  { float wv_ = (wv);                                             \
    a0 += wv_ * __uint_as_float((unsigned)(vv)[0] << 16);         \
    a1 += wv_ * __uint_as_float((unsigned)(vv)[1] << 16);         \
    a2 += wv_ * __uint_as_float((unsigned)(vv)[2] << 16);         \
    a3 += wv_ * __uint_as_float((unsigned)(vv)[3] << 16);         \
    a4 += wv_ * __uint_as_float((unsigned)(vv)[4] << 16);         \
    a5 += wv_ * __uint_as_float((unsigned)(vv)[5] << 16);         \
    a6 += wv_ * __uint_as_float((unsigned)(vv)[6] << 16);         \
    a7 += wv_ * __uint_as_float((unsigned)(vv)[7] << 16); }

__global__ __launch_bounds__(NTHREADS, 4) void decoder_kernel(
    const float* __restrict__ prev, const int* __restrict__ pidx,
    const float* __restrict__ w, const float* __restrict__ b,
    const float* __restrict__ actf, float* __restrict__ out) {
  extern __shared__ char xb[];               // [2048 rows][48 B] bf16 tile
  const int tid  = threadIdx.x;
  const int bid  = blockIdx.x;               // 0..255 (= tile)
  const int pos0 = bid * POS_TILE;

  // ---- stage prev[:, pos0:pos0+16] as bf16-RNE into 48B padded rows ----
  #pragma unroll
  for (int it = 0; it < 4; ++it) {
    int ci = (it << 10) + tid;               // 0..4095 (= r*2 + c)
    int r = ci >> 1, c = ci & 1;
    const float* sp = prev + r * NN + pos0 + (c << 3);
    f32x4 v0 = *(const f32x4*)sp;
    f32x4 v1 = *(const f32x4*)(sp + 4);
    u16x8 o;
    o[0] = f2bf_rne(v0.x); o[1] = f2bf_rne(v0.y);
    o[2] = f2bf_rne(v0.z); o[3] = f2bf_rne(v0.w);
    o[4] = f2bf_rne(v1.x); o[5] = f2bf_rne(v1.y);
    o[6] = f2bf_rne(v1.z); o[7] = f2bf_rne(v1.w);
    *(u16x8*)(xb + r * ROW_B + (c << 4)) = o;   // 16B-aligned (48 = 3*16)
  }
  __syncthreads();

  const int q  = tid & 1;                    // 16B chunk = 8 positions
  const int s  = tid >> 1;                   // node slot 0..511
  const int qb = q << 4;                     // byte offset within row

  // ---- prologue: tables for it=0 ----
  const int4*   ip0 = (const int4*)(pidx + (s << 4));
  const float4* wp0 = (const float4*)(w + (s << 4));
  int4   ci0 = ip0[0], ci1 = ip0[1], ci2 = ip0[2], ci3 = ip0[3];
  float4 cw0 = wp0[0], cw1 = wp0[1], cw2 = wp0[2], cw3 = wp0[3];
  float  cbk = b[s],   cg  = actf[s];

  for (int it = 0; it < 8; ++it) {
    // ---- prefetch next iteration's tables (clamped; uniform select) ----
    int nx = (it < 7 ? ((it + 1) << 9) : (7 << 9)) + s;
    const int4*   ipn = (const int4*)(pidx + (nx << 4));
    const float4* wpn = (const float4*)(w + (nx << 4));
    int4   ni0 = ipn[0], ni1 = ipn[1], ni2 = ipn[2], ni3 = ipn[3];
    float4 nw0 = wpn[0], nw1 = wpn[1], nw2 = wpn[2], nw3 = wpn[3];
    float  nbk = b[nx],  ng  = actf[nx];

    int n = (it << 9) + s;
    float a0 = cbk, a1 = cbk, a2 = cbk, a3 = cbk;
    float a4 = cbk, a5 = cbk, a6 = cbk, a7 = cbk;

    // batch 1: parents 0..7 — 8 independent ds_read_b128
    u16x8 v0 = *(const u16x8*)(xb + ci0.x * ROW_B + qb);
    u16x8 v1 = *(const u16x8*)(xb + ci0.y * ROW_B + qb);
    u16x8 v2 = *(const u16x8*)(xb + ci0.z * ROW_B + qb);
    u16x8 v3 = *(const u16x8*)(xb + ci0.w * ROW_B + qb);
    u16x8 v4 = *(const u16x8*)(xb + ci1.x * ROW_B + qb);
    u16x8 v5 = *(const u16x8*)(xb + ci1.y * ROW_B + qb);
    u16x8 v6 = *(const u16x8*)(xb + ci1.z * ROW_B + qb);
    u16x8 v7 = *(const u16x8*)(xb + ci1.w * ROW_B + qb);
    __builtin_amdgcn_sched_barrier(0);       // loads (incl. prefetch) stay above
    PFMA(v0, cw0.x) PFMA(v1, cw0.y) PFMA(v2, cw0.z) PFMA(v3, cw0.w)
    PFMA(v4, cw1.x) PFMA(v5, cw1.y) PFMA(v6, cw1.z) PFMA(v7, cw1.w)

    // batch 2: parents 8..15 (issued between barriers -> overlaps batch-1 FMA)
    v0 = *(const u16x8*)(xb + ci2.x * ROW_B + qb);
    v1 = *(const u16x8*)(xb + ci2.y * ROW_B + qb);
    v2 = *(const u16x8*)(xb + ci2.z * ROW_B + qb);
    v3 = *(const u16x8*)(xb + ci2.w * ROW_B + qb);
    v4 = *(const u16x8*)(xb + ci3.x * ROW_B + qb);
    v5 = *(const u16x8*)(xb + ci3.y * ROW_B + qb);
    v6 = *(const u16x8*)(xb + ci3.z * ROW_B + qb);
    v7 = *(const u16x8*)(xb + ci3.w * ROW_B + qb);
    __builtin_amdgcn_sched_barrier(0);
    PFMA(v0, cw2.x) PFMA(v1, cw2.y) PFMA(v2, cw2.z) PFMA(v3, cw2.w)
    PFMA(v4, cw3.x) PFMA(v5, cw3.y) PFMA(v6, cw3.z) PFMA(v7, cw3.w)

    f32x4 o0, o1;
    o0.x = fast_tanh(a0) * cg; o0.y = fast_tanh(a1) * cg;
    o0.z = fast_tanh(a2) * cg; o0.w = fast_tanh(a3) * cg;
    o1.x = fast_tanh(a4) * cg; o1.y = fast_tanh(a5) * cg;
    o1.z = fast_tanh(a6) * cg; o1.w = fast_tanh(a7) * cg;

    // pair writes node n's full 64B line (lane covers 32B)
    float* op = out + ((size_t)n << 12) + pos0 + (q << 3);
    *(f32x4*)op       = o0;
    *(f32x4*)(op + 4) = o1;

    // rotate next -> current (SSA renames, no real moves)
    ci0 = ni0; ci1 = ni1; ci2 = ni2; ci3 = ni3;
    cw0 = nw0; cw1 = nw1; cw2 = nw2; cw3 = nw3;
    cbk = nbk; cg = ng;
  }
}

extern "C" void kernel_launch(void* const* d_in, const int* in_sizes, int n_in,
                              void* d_out, int out_size, void* d_ws, size_t ws_size,
                              hipStream_t stream) {
  const float* prev  = (const float*)d_in[0];
  const void*  isact = d_in[1];
  const int*   pidx  = (const int*)d_in[2];
  const float* w     = (const float*)d_in[3];
  const float* b     = (const float*)d_in[4];
  float* out    = (float*)d_out;
  float* outact = out + OUT_ELEMS;           // act_kernel writes the gate vector

  (void)hipFuncSetAttribute((const void*)decoder_kernel,
                            hipFuncAttributeMaxDynamicSharedMemorySize, LDS_BYTES);

  act_kernel<<<K_NODES / 256, 256, 0, stream>>>(
      pidx, (const unsigned int*)isact, outact);
  decoder_kernel<<<NN / POS_TILE, NTHREADS, LDS_BYTES, stream>>>(
      prev, pidx, w, b, outact, out);
}